// Round 28
// baseline (202.939 us; speedup 1.0000x reference)
//
#include <hip/hip_runtime.h>

typedef unsigned short u16;
typedef unsigned int u32;
typedef __attribute__((ext_vector_type(2))) unsigned int u32x2;
typedef __attribute__((ext_vector_type(8))) short bf16x8;
typedef __attribute__((ext_vector_type(4))) float f32x4;
typedef __attribute__((ext_vector_type(16))) float f32x16;
typedef __attribute__((ext_vector_type(4))) unsigned short u16x4;

#define MFMA16(a, b, c) __builtin_amdgcn_mfma_f32_16x16x32_bf16((a), (b), (c), 0, 0, 0)
#define MFMA32(a, b, c) __builtin_amdgcn_mfma_f32_32x32x16_bf16((a), (b), (c), 0, 0, 0)

__device__ __forceinline__ u16 f2bf(float f) {
  union { float f; unsigned int i; } v; v.f = f;
  return (u16)((v.i + 0x7FFFu + ((v.i >> 16) & 1u)) >> 16);
}
__device__ __forceinline__ float exp2a(float x) {  // raw v_exp_f32 (2^x)
  float r; asm("v_exp_f32 %0, %1" : "=v"(r) : "v"(x)); return r;
}
__device__ __forceinline__ u32 cvtpk(float lo, float hi) {  // [bf16(lo) | bf16(hi)<<16]
  u32 d; asm("v_cvt_pk_bf16_f32 %0, %1, %2" : "=v"(d) : "v"(lo), "v"(hi)); return d;
}
// async global->LDS, 16B per lane; lds dest = wave-uniform base + lane*16 (m104)
__device__ __forceinline__ void gl2lds16(const u16* g, u16* l) {
  __builtin_amdgcn_global_load_lds(
      (const __attribute__((address_space(1))) void*)g,
      (__attribute__((address_space(3))) void*)l, 16, 0, 0);
}

// ---------------- prep: ingest x (fp32->bf16) + transpose both weights, one launch ----------------
__global__ __launch_bounds__(256) void k_prep(const float* __restrict__ x,
                                              u16* __restrict__ xb,
                                              const float* __restrict__ w_qkv,
                                              u16* __restrict__ wqkvT,
                                              const float* __restrict__ w_proj,
                                              u16* __restrict__ wprojT) {
  const int id = (int)blockIdx.x;
  const int t = threadIdx.x;
  if (id < 4096) {
    const int i = id * 256 + t;
    const float* s = x + (size_t)i * 8;
    float4 a = *(const float4*)(s);
    float4 b = *(const float4*)(s + 4);
    union { u16 o[8]; int4 v; } u;
    u.o[0] = f2bf(a.x); u.o[1] = f2bf(a.y); u.o[2] = f2bf(a.z); u.o[3] = f2bf(a.w);
    u.o[4] = f2bf(b.x); u.o[5] = f2bf(b.y); u.o[6] = f2bf(b.z); u.o[7] = f2bf(b.w);
    *(int4*)(&xb[(size_t)i * 8]) = u.v;
    return;
  }
  __shared__ u16 tile[64][65];
  const float* src;
  u16* dst;
  int R, C, c0, r0;
  if (id < 4864) {
    const int q = id - 4096;
    src = w_qkv; dst = wqkvT; R = 1024; C = 3072;
    c0 = (q % 48) * 64; r0 = (q / 48) * 64;
  } else {
    const int q = id - 4864;
    src = w_proj; dst = wprojT; R = 1024; C = 1024;
    c0 = (q % 16) * 64; r0 = (q / 16) * 64;
  }
#pragma unroll
  for (int i = 0; i < 16; ++i) {
    int e = i * 256 + t, rr = e >> 6, cc = e & 63;
    tile[rr][cc] = f2bf(src[(size_t)(r0 + rr) * C + c0 + cc]);
  }
  __syncthreads();
#pragma unroll
  for (int i = 0; i < 16; ++i) {
    int e = i * 256 + t, rr = e >> 6, cc = e & 63;
    dst[(size_t)(c0 + rr) * R + r0 + cc] = tile[cc][rr];
  }
}

// ---------------- GEMM (m97 structure + T1 XCD bm-chunking, BK=32) ----------------
template <int QKV>
__global__ __launch_bounds__(256) void k_gemm(
    const u16* __restrict__ A, const u16* __restrict__ Bt,
    const float* __restrict__ bias, float* __restrict__ Cf,
    u16* __restrict__ Qb, u16* __restrict__ Kb, u16* __restrict__ VTb,
    int M, int N, int K, int BNn) {
  __shared__ __attribute__((aligned(16))) u16 As[128 * 32];  // [row][k]
  __shared__ __attribute__((aligned(16))) u16 Bs[128 * 32];  // [col][k]
  const int wg = (int)blockIdx.x;
  const int xcd = wg & 7, loc = wg >> 3;
  const int bmPerXcd = (M >> 7) >> 3;
  const int bm = xcd * bmPerXcd + loc / BNn;
  const int bn = loc % BNn;
  const int t = threadIdx.x, lane = t & 63, w = t >> 6;
  const int wr = w >> 1, wc = w & 1;        // 2x2 wave grid, 64x64 per wave
  const int rh = lane & 15, kg = lane >> 4; // fragment row / k-group
  const int srow = lane >> 2, sk8 = (lane & 3) << 3;  // staging: lane -> row, k-offset

  f32x4 acc[4][4];
#pragma unroll
  for (int mi = 0; mi < 4; ++mi)
#pragma unroll
    for (int ni = 0; ni < 4; ++ni) acc[mi][ni] = (f32x4)0.0f;

  for (int k0 = 0; k0 < K; k0 += 32) {
#pragma unroll
    for (int i = 0; i < 2; ++i) {
      const int r0 = w * 32 + i * 16;  // segment base row (wave-uniform)
      gl2lds16(&A[(size_t)(bm * 128 + r0 + srow) * K + k0 + sk8], &As[r0 * 32]);
      gl2lds16(&Bt[(size_t)(bn * 128 + r0 + srow) * K + k0 + sk8], &Bs[r0 * 32]);
    }
    asm volatile("s_waitcnt vmcnt(0)" ::: "memory");
    __syncthreads();

    bf16x8 af[4], bfr[4];
#pragma unroll
    for (int mi = 0; mi < 4; ++mi)
      af[mi] = *(const bf16x8*)(&As[(wr * 64 + mi * 16 + rh) * 32 + kg * 8]);
#pragma unroll
    for (int ni = 0; ni < 4; ++ni)
      bfr[ni] = *(const bf16x8*)(&Bs[(wc * 64 + ni * 16 + rh) * 32 + kg * 8]);
    __builtin_amdgcn_s_setprio(1);
#pragma unroll
    for (int mi = 0; mi < 4; ++mi)
#pragma unroll
      for (int ni = 0; ni < 4; ++ni)
        acc[mi][ni] = MFMA16(af[mi], bfr[ni], acc[mi][ni]);
    __builtin_amdgcn_s_setprio(0);
    __syncthreads();
  }

  if (QKV == 0) {
    const int rbase = bm * 128 + wr * 64;
    const int cbase = bn * 128 + wc * 64;
#pragma unroll
    for (int ni = 0; ni < 4; ++ni) {
      const int col = cbase + ni * 16 + rh;
      const float bv = bias ? bias[col] : 0.0f;
#pragma unroll
      for (int mi = 0; mi < 4; ++mi) {
#pragma unroll
        for (int r = 0; r < 4; ++r) {
          int row = rbase + mi * 16 + kg * 4 + r;
          Cf[(size_t)row * N + col] = acc[mi][ni][r] + bv;
        }
      }
    }
  } else {
    const float SCQ = 0.125f * 1.44269504f;  // qk-scale * log2(e), folded into Q
    const int rowbase = bm * 128 + wr * 64;
    const int b = rowbase >> 11;
    const int tb = rowbase & 2047;
    const int cbase = bn * 128 + wc * 64;
    const int role = cbase >> 10;
    const int h = (cbase & 1023) >> 6;
    const int bh = b * 16 + h;
#pragma unroll
    for (int ni = 0; ni < 4; ++ni) {
      const int d = ni * 16 + rh;
#pragma unroll
      for (int mi = 0; mi < 4; ++mi) {
        const int tt = tb + mi * 16 + kg * 4;
        if (role == 2) {
          u16x4 pk;
#pragma unroll
          for (int r = 0; r < 4; ++r) pk[r] = f2bf(acc[mi][ni][r]);
          *(u16x4*)(&VTb[((size_t)bh * 64 + d) * 2048 + tt]) = pk;  // V^T[bh][d][t]
        } else {
          u16* dst = (role == 0) ? Qb : Kb;
          const float sc = (role == 0) ? SCQ : 1.0f;
#pragma unroll
          for (int r = 0; r < 4; ++r)
            dst[((size_t)bh * 2048 + tt + r) * 64 + d] = f2bf(acc[mi][ni][r] * sc);
        }
      }
    }
  }
}

// ---------------- causal flash attention: deferred-PV pipeline (T15 depth-1) ----------------
// Iteration t: issue QK(t), then PV(t-1) (carried pa frags), then softmax(t).
// PV(t-1) & QK(t) are independent of SM(t) -> MFMA pipe stays busy during the ~300cyc
// serial VALU softmax (T15 mechanism). PV(t-1) precedes any rescale at t in program
// order, so flash algebra is unchanged. K-prefetch + permlane pack as r24/r27.
__global__ __launch_bounds__(64, 2) void k_attn(const u16* __restrict__ Qb,
                                                const u16* __restrict__ Kb,
                                                const u16* __restrict__ VTb,
                                                u16* __restrict__ Y) {
  const int bh = blockIdx.x;
  const int sb = 31 - (int)blockIdx.y;  // LPT: big superblocks dispatch first
  const int lane = threadIdx.x & 63;
  const int q31 = lane & 31, hi = lane >> 5;
  const int qA = sb * 64 + q31;        // MFMA block A row
  const int qBr = sb * 64 + 32 + q31;  // MFMA block B row
  const u16* Qh = Qb + (size_t)bh * 2048 * 64;
  const u16* Kh = Kb + (size_t)bh * 2048 * 64;
  const u16* Vh = VTb + (size_t)bh * 64 * 2048;
  const int b = bh >> 4, h = bh & 15;

  bf16x8 qfA[4], qfB[4];
#pragma unroll
  for (int d = 0; d < 4; ++d) {
    qfA[d] = *(const bf16x8*)(&Qh[(size_t)qA * 64 + d * 16 + hi * 8]);
    qfB[d] = *(const bf16x8*)(&Qh[(size_t)qBr * 64 + d * 16 + hi * 8]);
  }

  f32x16 oA0 = (f32x16)0.0f, oA1 = (f32x16)0.0f;
  f32x16 oB0 = (f32x16)0.0f, oB1 = (f32x16)0.0f;
  float mA = -1e30f, sA = 0.0f, mB = -1e30f, sB = 0.0f;

  const int nt = 2 * sb + 2;  // always even, >= 2
  bf16x8 kf[4], kn[4];
#pragma unroll
  for (int d = 0; d < 4; ++d)
    kf[d] = *(const bf16x8*)(&Kh[(size_t)q31 * 64 + d * 16 + hi * 8]);

  union U { u32 w4[4]; bf16x8 f; };
  U paA0, paA1, paB0, paB1;  // carried P fragments (tile t-1)

  // ---- prologue: tile 0 = QK + SM only (PV deferred to iteration 1) ----
  {
#pragma unroll
    for (int d = 0; d < 4; ++d)
      kn[d] = *(const bf16x8*)(&Kh[(size_t)(32 + q31) * 64 + d * 16 + hi * 8]);

    f32x16 stB = (f32x16)0.0f;
    __builtin_amdgcn_s_setprio(1);
#pragma unroll
    for (int d = 0; d < 4; ++d) stB = MFMA32(kf[d], qfB[d], stB);
    f32x16 stA = (f32x16)0.0f;
#pragma unroll
    for (int d = 0; d < 4; ++d) stA = MFMA32(kf[d], qfA[d], stA);
    __builtin_amdgcn_s_setprio(0);

    if (nt == 2) {  // tile 0 is A's diagonal
#pragma unroll
      for (int r = 0; r < 16; ++r) {
        const int kcol = (r & 3) + 8 * (r >> 2) + 4 * hi;
        if (kcol > q31) stA[r] = -1e30f;
      }
    }
    {  // SM-A
      float mx = fmaxf(
          fmaxf(fmaxf(fmaxf(stA[0], stA[1]), fmaxf(stA[2], stA[3])),
                fmaxf(fmaxf(stA[4], stA[5]), fmaxf(stA[6], stA[7]))),
          fmaxf(fmaxf(fmaxf(stA[8], stA[9]), fmaxf(stA[10], stA[11])),
                fmaxf(fmaxf(stA[12], stA[13]), fmaxf(stA[14], stA[15]))));
      if (__any(mx - mA > 8.0f)) {
        mx = fmaxf(mx, __shfl_xor(mx, 32));
        const float mn = fmaxf(mA, mx);
        const float scf = exp2a(mA - mn);
        mA = mn; sA *= scf; oA0 *= scf; oA1 *= scf;
      }
      float p[16];
#pragma unroll
      for (int r = 0; r < 16; ++r) p[r] = exp2a(stA[r] - mA);
      sA += (((p[0] + p[1]) + (p[2] + p[3])) + ((p[4] + p[5]) + (p[6] + p[7]))) +
            (((p[8] + p[9]) + (p[10] + p[11])) + ((p[12] + p[13]) + (p[14] + p[15])));
      u32 D0 = cvtpk(p[0], p[1]),   D1 = cvtpk(p[2], p[3]);
      u32 D2 = cvtpk(p[4], p[5]),   D3 = cvtpk(p[6], p[7]);
      u32 D4 = cvtpk(p[8], p[9]),   D5 = cvtpk(p[10], p[11]);
      u32 D6 = cvtpk(p[12], p[13]), D7 = cvtpk(p[14], p[15]);
      u32x2 s02 = __builtin_amdgcn_permlane32_swap(D0, D2, false, false);
      u32x2 s13 = __builtin_amdgcn_permlane32_swap(D1, D3, false, false);
      u32x2 s46 = __builtin_amdgcn_permlane32_swap(D4, D6, false, false);
      u32x2 s57 = __builtin_amdgcn_permlane32_swap(D5, D7, false, false);
      paA0.w4[0] = s02.x; paA0.w4[1] = s13.x; paA0.w4[2] = s02.y; paA0.w4[3] = s13.y;
      paA1.w4[0] = s46.x; paA1.w4[1] = s57.x; paA1.w4[2] = s46.y; paA1.w4[3] = s57.y;
    }
    {  // SM-B
      float mx = fmaxf(
          fmaxf(fmaxf(fmaxf(stB[0], stB[1]), fmaxf(stB[2], stB[3])),
                fmaxf(fmaxf(stB[4], stB[5]), fmaxf(stB[6], stB[7]))),
          fmaxf(fmaxf(fmaxf(stB[8], stB[9]), fmaxf(stB[10], stB[11])),
                fmaxf(fmaxf(stB[12], stB[13]), fmaxf(stB[14], stB[15]))));
      if (__any(mx - mB > 8.0f)) {
        mx = fmaxf(mx, __shfl_xor(mx, 32));
        const float mn = fmaxf(mB, mx);
        const float scf = exp2a(mB - mn);
        mB = mn; sB *= scf; oB0 *= scf; oB1 *= scf;
      }
      float p[16];
#pragma unroll
      for (int r = 0; r < 16; ++r) p[r] = exp2a(stB[r] - mB);
      sB += (((p[0] + p[1]) + (p[2] + p[3])) + ((p[4] + p[5]) + (p[6] + p[7]))) +
            (((p[8] + p[9]) + (p[10] + p[11])) + ((p[12] + p[13]) + (p[14] + p[15])));
      u32 D0 = cvtpk(p[0], p[1]),   D1 = cvtpk(p[2], p[3]);
      u32 D2 = cvtpk(p[4], p[5]),   D3 = cvtpk(p[6], p[7]);
      u32 D4 = cvtpk(p[8], p[9]),   D5 = cvtpk(p[10], p[11]);
      u32 D6 = cvtpk(p[12], p[13]), D7 = cvtpk(p[14], p[15]);
      u32x2 s02 = __builtin_amdgcn_permlane32_swap(D0, D2, false, false);
      u32x2 s13 = __builtin_amdgcn_permlane32_swap(D1, D3, false, false);
      u32x2 s46 = __builtin_amdgcn_permlane32_swap(D4, D6, false, false);
      u32x2 s57 = __builtin_amdgcn_permlane32_swap(D5, D7, false, false);
      paB0.w4[0] = s02.x; paB0.w4[1] = s13.x; paB0.w4[2] = s02.y; paB0.w4[3] = s13.y;
      paB1.w4[0] = s46.x; paB1.w4[1] = s57.x; paB1.w4[2] = s46.y; paB1.w4[3] = s57.y;
    }
#pragma unroll
    for (int d = 0; d < 4; ++d) kf[d] = kn[d];
  }

  // ---- main loop: t = 1..nt-1; PV lags by one tile ----
  for (int tt = 1; tt < nt; ++tt) {
    const int jp = (tt - 1) * 32;  // V tile for the deferred PV
    const int jn = (tt + 1 < nt) ? (tt + 1) * 32 : tt * 32;
    const bool aAct = tt < nt - 1;  // A active for QK/SM at tile tt

    // V(t-1) early; K(t+1) prefetch
    const bf16x8 vf0 = *(const bf16x8*)(&Vh[(size_t)q31 * 2048 + jp + hi * 8]);
    const bf16x8 vf1 = *(const bf16x8*)(&Vh[(size_t)q31 * 2048 + jp + 16 + hi * 8]);
    const bf16x8 vf2 = *(const bf16x8*)(&Vh[(size_t)(32 + q31) * 2048 + jp + hi * 8]);
    const bf16x8 vf3 = *(const bf16x8*)(&Vh[(size_t)(32 + q31) * 2048 + jp + 16 + hi * 8]);
#pragma unroll
    for (int d = 0; d < 4; ++d)
      kn[d] = *(const bf16x8*)(&Kh[(size_t)(jn + q31) * 64 + d * 16 + hi * 8]);

    // QK(t)
    f32x16 stB = (f32x16)0.0f;
    __builtin_amdgcn_s_setprio(1);
#pragma unroll
    for (int d = 0; d < 4; ++d) stB = MFMA32(kf[d], qfB[d], stB);
    f32x16 stA = (f32x16)0.0f;
    if (aAct) {
#pragma unroll
      for (int d = 0; d < 4; ++d) stA = MFMA32(kf[d], qfA[d], stA);
    }
    // PV(t-1): independent of SM(t) -> fills the MFMA pipe during the VALU softmax
    oB0 = MFMA32(vf0, paB0.f, oB0);
    oB0 = MFMA32(vf1, paB1.f, oB0);
    oB1 = MFMA32(vf2, paB0.f, oB1);
    oB1 = MFMA32(vf3, paB1.f, oB1);
    oA0 = MFMA32(vf0, paA0.f, oA0);
    oA0 = MFMA32(vf1, paA1.f, oA0);
    oA1 = MFMA32(vf2, paA0.f, oA1);
    oA1 = MFMA32(vf3, paA1.f, oA1);
    __builtin_amdgcn_s_setprio(0);

    if (tt == nt - 2) {
#pragma unroll
      for (int r = 0; r < 16; ++r) {
        const int kcol = (r & 3) + 8 * (r >> 2) + 4 * hi;
        if (kcol > q31) stA[r] = -1e30f;
      }
    }
    if (tt == nt - 1) {
#pragma unroll
      for (int r = 0; r < 16; ++r) {
        const int kcol = (r & 3) + 8 * (r >> 2) + 4 * hi;
        if (kcol > q31) stB[r] = -1e30f;
      }
    }

    if (aAct) {  // SM-A(t) -> paA
      float mx = fmaxf(
          fmaxf(fmaxf(fmaxf(stA[0], stA[1]), fmaxf(stA[2], stA[3])),
                fmaxf(fmaxf(stA[4], stA[5]), fmaxf(stA[6], stA[7]))),
          fmaxf(fmaxf(fmaxf(stA[8], stA[9]), fmaxf(stA[10], stA[11])),
                fmaxf(fmaxf(stA[12], stA[13]), fmaxf(stA[14], stA[15]))));
      if (__any(mx - mA > 8.0f)) {
        mx = fmaxf(mx, __shfl_xor(mx, 32));
        const float mn = fmaxf(mA, mx);
        const float scf = exp2a(mA - mn);
        mA = mn; sA *= scf; oA0 *= scf; oA1 *= scf;
      }
      float p[16];
#pragma unroll
      for (int r = 0; r < 16; ++r) p[r] = exp2a(stA[r] - mA);
      sA += (((p[0] + p[1]) + (p[2] + p[3])) + ((p[4] + p[5]) + (p[6] + p[7]))) +
            (((p[8] + p[9]) + (p[10] + p[11])) + ((p[12] + p[13]) + (p[14] + p[15])));
      u32 D0 = cvtpk(p[0], p[1]),   D1 = cvtpk(p[2], p[3]);
      u32 D2 = cvtpk(p[4], p[5]),   D3 = cvtpk(p[6], p[7]);
      u32 D4 = cvtpk(p[8], p[9]),   D5 = cvtpk(p[10], p[11]);
      u32 D6 = cvtpk(p[12], p[13]), D7 = cvtpk(p[14], p[15]);
      u32x2 s02 = __builtin_amdgcn_permlane32_swap(D0, D2, false, false);
      u32x2 s13 = __builtin_amdgcn_permlane32_swap(D1, D3, false, false);
      u32x2 s46 = __builtin_amdgcn_permlane32_swap(D4, D6, false, false);
      u32x2 s57 = __builtin_amdgcn_permlane32_swap(D5, D7, false, false);
      paA0.w4[0] = s02.x; paA0.w4[1] = s13.x; paA0.w4[2] = s02.y; paA0.w4[3] = s13.y;
      paA1.w4[0] = s46.x; paA1.w4[1] = s57.x; paA1.w4[2] = s46.y; paA1.w4[3] = s57.y;
    }

    {  // SM-B(t) -> paB
      float mx = fmaxf(
          fmaxf(fmaxf(fmaxf(stB[0], stB[1]), fmaxf(stB[2], stB[3])),
                fmaxf(fmaxf(stB[4], stB[5]), fmaxf(stB[6], stB[7]))),
          fmaxf(fmaxf(fmaxf(stB[8], stB[9]), fmaxf(stB[10], stB[11])),
                fmaxf(fmaxf(stB[12], stB[13]), fmaxf(stB[14], stB[15]))));
      if (__any(mx - mB > 8.0f)) {
        mx = fmaxf(mx, __shfl_xor(mx, 32));
        const float mn = fmaxf(mB, mx);
        const float scf = exp2a(mB - mn);
        mB = mn; sB *= scf; oB0 *= scf; oB1 *= scf;
      }
      float p[16];
#pragma unroll
      for (int r = 0; r < 16; ++r) p[r] = exp2a(stB[r] - mB);
      sB += (((p[0] + p[1]) + (p[2] + p[3])) + ((p[4] + p[5]) + (p[6] + p[7]))) +
            (((p[8] + p[9]) + (p[10] + p[11])) + ((p[12] + p[13]) + (p[14] + p[15])));
      u32 D0 = cvtpk(p[0], p[1]),   D1 = cvtpk(p[2], p[3]);
      u32 D2 = cvtpk(p[4], p[5]),   D3 = cvtpk(p[6], p[7]);
      u32 D4 = cvtpk(p[8], p[9]),   D5 = cvtpk(p[10], p[11]);
      u32 D6 = cvtpk(p[12], p[13]), D7 = cvtpk(p[14], p[15]);
      u32x2 s02 = __builtin_amdgcn_permlane32_swap(D0, D2, false, false);
      u32x2 s13 = __builtin_amdgcn_permlane32_swap(D1, D3, false, false);
      u32x2 s46 = __builtin_amdgcn_permlane32_swap(D4, D6, false, false);
      u32x2 s57 = __builtin_amdgcn_permlane32_swap(D5, D7, false, false);
      paB0.w4[0] = s02.x; paB0.w4[1] = s13.x; paB0.w4[2] = s02.y; paB0.w4[3] = s13.y;
      paB1.w4[0] = s46.x; paB1.w4[1] = s57.x; paB1.w4[2] = s46.y; paB1.w4[3] = s57.y;
    }

#pragma unroll
    for (int d = 0; d < 4; ++d) kf[d] = kn[d];
  }

  // ---- flush: PV of tile nt-1 (B only; A's last tile is fully masked) ----
  {
    const int jp = (nt - 1) * 32;
    const bf16x8 vf0 = *(const bf16x8*)(&Vh[(size_t)q31 * 2048 + jp + hi * 8]);
    const bf16x8 vf1 = *(const bf16x8*)(&Vh[(size_t)q31 * 2048 + jp + 16 + hi * 8]);
    const bf16x8 vf2 = *(const bf16x8*)(&Vh[(size_t)(32 + q31) * 2048 + jp + hi * 8]);
    const bf16x8 vf3 = *(const bf16x8*)(&Vh[(size_t)(32 + q31) * 2048 + jp + 16 + hi * 8]);
    __builtin_amdgcn_s_setprio(1);
    oB0 = MFMA32(vf0, paB0.f, oB0);
    oB0 = MFMA32(vf1, paB1.f, oB0);
    oB1 = MFMA32(vf2, paB0.f, oB1);
    oB1 = MFMA32(vf3, paB1.f, oB1);
    __builtin_amdgcn_s_setprio(0);
  }

  sA += __shfl_xor(sA, 32);
  sB += __shfl_xor(sB, 32);
  const float invA = 1.0f / sA, invB = 1.0f / sB;
  u16* yrowA = Y + ((size_t)b * 2048 + qA) * 1024 + h * 64;
  u16* yrowB = Y + ((size_t)b * 2048 + qBr) * 1024 + h * 64;
#pragma unroll
  for (int a = 0; a < 4; ++a) {
    u16x4 pk;
#pragma unroll
    for (int i = 0; i < 4; ++i) pk[i] = f2bf(oA0[a * 4 + i] * invA);
    *(u16x4*)(yrowA + a * 8 + 4 * hi) = pk;
#pragma unroll
    for (int i = 0; i < 4; ++i) pk[i] = f2bf(oA1[a * 4 + i] * invA);
    *(u16x4*)(yrowA + 32 + a * 8 + 4 * hi) = pk;
#pragma unroll
    for (int i = 0; i < 4; ++i) pk[i] = f2bf(oB0[a * 4 + i] * invB);
    *(u16x4*)(yrowB + a * 8 + 4 * hi) = pk;
#pragma unroll
    for (int i = 0; i < 4; ++i) pk[i] = f2bf(oB1[a * 4 + i] * invB);
    *(u16x4*)(yrowB + 32 + a * 8 + 4 * hi) = pk;
  }
}

extern "C" void kernel_launch(void* const* d_in, const int* in_sizes, int n_in,
                              void* d_out, int out_size, void* d_ws, size_t ws_size,
                              hipStream_t stream) {
  const float* x      = (const float*)d_in[0];  // [4,2048,1024] fp32
  const float* w_qkv  = (const float*)d_in[1];  // [1024,3072]   fp32
  const float* w_proj = (const float*)d_in[2];  // [1024,1024]   fp32
  const float* b_proj = (const float*)d_in[3];  // [1024]        fp32
  float* out = (float*)d_out;                   // [4,2048,1024] fp32

  char* ws = (char*)d_ws;
  u16* wqkvT  = (u16*)(ws);             // [3072][1024] bf16  6.29 MB
  u16* wprojT = (u16*)(ws + 6291456);   // [1024][1024] bf16  2.10 MB
  u16* Qb     = (u16*)(ws + 8388608);   // [64][2048][64]    16.78 MB
  u16* Kb     = (u16*)(ws + 25165824);  // [64][2048][64]    16.78 MB
  u16* VTb    = (u16*)(ws + 41943040);  // [64][64][2048]    16.78 MB
  u16* xb     = (u16*)(ws + 58720256);  // [8192][1024] bf16 16.78 MB (aliased: xb then Yb)
  u16* Yb     = xb;                     // xb dead after GEMM1; attn writes Yb

  k_prep<<<5120, 256, 0, stream>>>(x, xb, w_qkv, wqkvT, w_proj, wprojT);
  k_gemm<1><<<1536, 256, 0, stream>>>(xb, wqkvT, nullptr, nullptr,
                                      Qb, Kb, VTb, 8192, 3072, 1024, 24);
  k_attn<<<dim3(64, 32), 64, 0, stream>>>(Qb, Kb, VTb, Yb);
  k_gemm<0><<<512, 256, 0, stream>>>(Yb, wprojT, b_proj, out,
                                     nullptr, nullptr, nullptr, 8192, 1024, 1024, 8);
}

// Round 29
// 200.551 us; speedup vs baseline: 1.0119x; 1.0119x over previous
//
#include <hip/hip_runtime.h>

typedef unsigned short u16;
typedef unsigned int u32;
typedef __attribute__((ext_vector_type(2))) unsigned int u32x2;
typedef __attribute__((ext_vector_type(8))) short bf16x8;
typedef __attribute__((ext_vector_type(4))) float f32x4;
typedef __attribute__((ext_vector_type(16))) float f32x16;
typedef __attribute__((ext_vector_type(4))) unsigned short u16x4;

#define MFMA16(a, b, c) __builtin_amdgcn_mfma_f32_16x16x32_bf16((a), (b), (c), 0, 0, 0)
#define MFMA32(a, b, c) __builtin_amdgcn_mfma_f32_32x32x16_bf16((a), (b), (c), 0, 0, 0)

__device__ __forceinline__ u16 f2bf(float f) {
  union { float f; unsigned int i; } v; v.f = f;
  return (u16)((v.i + 0x7FFFu + ((v.i >> 16) & 1u)) >> 16);
}
__device__ __forceinline__ float exp2a(float x) {  // raw v_exp_f32 (2^x)
  float r; asm("v_exp_f32 %0, %1" : "=v"(r) : "v"(x)); return r;
}
__device__ __forceinline__ u32 cvtpk(float lo, float hi) {  // [bf16(lo) | bf16(hi)<<16]
  u32 d; asm("v_cvt_pk_bf16_f32 %0, %1, %2" : "=v"(d) : "v"(lo), "v"(hi)); return d;
}
// async global->LDS, 16B per lane; lds dest = wave-uniform base + lane*16 (m104)
__device__ __forceinline__ void gl2lds16(const u16* g, u16* l) {
  __builtin_amdgcn_global_load_lds(
      (const __attribute__((address_space(1))) void*)g,
      (__attribute__((address_space(3))) void*)l, 16, 0, 0);
}

// ---------------- prep: ingest x (fp32->bf16) + transpose both weights, one launch ----------------
__global__ __launch_bounds__(256) void k_prep(const float* __restrict__ x,
                                              u16* __restrict__ xb,
                                              const float* __restrict__ w_qkv,
                                              u16* __restrict__ wqkvT,
                                              const float* __restrict__ w_proj,
                                              u16* __restrict__ wprojT) {
  const int id = (int)blockIdx.x;
  const int t = threadIdx.x;
  if (id < 4096) {
    const int i = id * 256 + t;
    const float* s = x + (size_t)i * 8;
    float4 a = *(const float4*)(s);
    float4 b = *(const float4*)(s + 4);
    union { u16 o[8]; int4 v; } u;
    u.o[0] = f2bf(a.x); u.o[1] = f2bf(a.y); u.o[2] = f2bf(a.z); u.o[3] = f2bf(a.w);
    u.o[4] = f2bf(b.x); u.o[5] = f2bf(b.y); u.o[6] = f2bf(b.z); u.o[7] = f2bf(b.w);
    *(int4*)(&xb[(size_t)i * 8]) = u.v;
    return;
  }
  __shared__ u16 tile[64][65];
  const float* src;
  u16* dst;
  int R, C, c0, r0;
  if (id < 4864) {
    const int q = id - 4096;
    src = w_qkv; dst = wqkvT; R = 1024; C = 3072;
    c0 = (q % 48) * 64; r0 = (q / 48) * 64;
  } else {
    const int q = id - 4864;
    src = w_proj; dst = wprojT; R = 1024; C = 1024;
    c0 = (q % 16) * 64; r0 = (q / 16) * 64;
  }
#pragma unroll
  for (int i = 0; i < 16; ++i) {
    int e = i * 256 + t, rr = e >> 6, cc = e & 63;
    tile[rr][cc] = f2bf(src[(size_t)(r0 + rr) * C + c0 + cc]);
  }
  __syncthreads();
#pragma unroll
  for (int i = 0; i < 16; ++i) {
    int e = i * 256 + t, rr = e >> 6, cc = e & 63;
    dst[(size_t)(c0 + rr) * R + r0 + cc] = tile[cc][rr];
  }
}

// ---------------- GEMM (m97 structure + T1 XCD bm-chunking, BK=32) ----------------
template <int QKV>
__global__ __launch_bounds__(256) void k_gemm(
    const u16* __restrict__ A, const u16* __restrict__ Bt,
    const float* __restrict__ bias, float* __restrict__ Cf,
    u16* __restrict__ Qb, u16* __restrict__ Kb, u16* __restrict__ VTb,
    int M, int N, int K, int BNn) {
  __shared__ __attribute__((aligned(16))) u16 As[128 * 32];  // [row][k]
  __shared__ __attribute__((aligned(16))) u16 Bs[128 * 32];  // [col][k]
  const int wg = (int)blockIdx.x;
  const int xcd = wg & 7, loc = wg >> 3;
  const int bmPerXcd = (M >> 7) >> 3;
  const int bm = xcd * bmPerXcd + loc / BNn;
  const int bn = loc % BNn;
  const int t = threadIdx.x, lane = t & 63, w = t >> 6;
  const int wr = w >> 1, wc = w & 1;        // 2x2 wave grid, 64x64 per wave
  const int rh = lane & 15, kg = lane >> 4; // fragment row / k-group
  const int srow = lane >> 2, sk8 = (lane & 3) << 3;  // staging: lane -> row, k-offset

  f32x4 acc[4][4];
#pragma unroll
  for (int mi = 0; mi < 4; ++mi)
#pragma unroll
    for (int ni = 0; ni < 4; ++ni) acc[mi][ni] = (f32x4)0.0f;

  for (int k0 = 0; k0 < K; k0 += 32) {
#pragma unroll
    for (int i = 0; i < 2; ++i) {
      const int r0 = w * 32 + i * 16;  // segment base row (wave-uniform)
      gl2lds16(&A[(size_t)(bm * 128 + r0 + srow) * K + k0 + sk8], &As[r0 * 32]);
      gl2lds16(&Bt[(size_t)(bn * 128 + r0 + srow) * K + k0 + sk8], &Bs[r0 * 32]);
    }
    asm volatile("s_waitcnt vmcnt(0)" ::: "memory");
    __syncthreads();

    bf16x8 af[4], bfr[4];
#pragma unroll
    for (int mi = 0; mi < 4; ++mi)
      af[mi] = *(const bf16x8*)(&As[(wr * 64 + mi * 16 + rh) * 32 + kg * 8]);
#pragma unroll
    for (int ni = 0; ni < 4; ++ni)
      bfr[ni] = *(const bf16x8*)(&Bs[(wc * 64 + ni * 16 + rh) * 32 + kg * 8]);
    __builtin_amdgcn_s_setprio(1);
#pragma unroll
    for (int mi = 0; mi < 4; ++mi)
#pragma unroll
      for (int ni = 0; ni < 4; ++ni)
        acc[mi][ni] = MFMA16(af[mi], bfr[ni], acc[mi][ni]);
    __builtin_amdgcn_s_setprio(0);
    __syncthreads();
  }

  if (QKV == 0) {
    const int rbase = bm * 128 + wr * 64;
    const int cbase = bn * 128 + wc * 64;
#pragma unroll
    for (int ni = 0; ni < 4; ++ni) {
      const int col = cbase + ni * 16 + rh;
      const float bv = bias ? bias[col] : 0.0f;
#pragma unroll
      for (int mi = 0; mi < 4; ++mi) {
#pragma unroll
        for (int r = 0; r < 4; ++r) {
          int row = rbase + mi * 16 + kg * 4 + r;
          Cf[(size_t)row * N + col] = acc[mi][ni][r] + bv;
        }
      }
    }
  } else {
    const float SCQ = 0.125f * 1.44269504f;  // qk-scale * log2(e), folded into Q
    const int rowbase = bm * 128 + wr * 64;
    const int b = rowbase >> 11;
    const int tb = rowbase & 2047;
    const int cbase = bn * 128 + wc * 64;
    const int role = cbase >> 10;
    const int h = (cbase & 1023) >> 6;
    const int bh = b * 16 + h;
#pragma unroll
    for (int ni = 0; ni < 4; ++ni) {
      const int d = ni * 16 + rh;
#pragma unroll
      for (int mi = 0; mi < 4; ++mi) {
        const int tt = tb + mi * 16 + kg * 4;
        if (role == 2) {
          u16x4 pk;
#pragma unroll
          for (int r = 0; r < 4; ++r) pk[r] = f2bf(acc[mi][ni][r]);
          *(u16x4*)(&VTb[((size_t)bh * 64 + d) * 2048 + tt]) = pk;  // V^T[bh][d][t]
        } else {
          u16* dst = (role == 0) ? Qb : Kb;
          const float sc = (role == 0) ? SCQ : 1.0f;
#pragma unroll
          for (int r = 0; r < 4; ++r)
            dst[((size_t)bh * 2048 + tt + r) * 64 + d] = f2bf(acc[mi][ni][r] * sc);
        }
      }
    }
  }
}

// ---------------- causal flash attention: K-prefetch + permlane32_swap P-pack (r24/r27) ----------------
__global__ __launch_bounds__(64, 2) void k_attn(const u16* __restrict__ Qb,
                                                const u16* __restrict__ Kb,
                                                const u16* __restrict__ VTb,
                                                u16* __restrict__ Y) {
  const int bh = blockIdx.x;
  const int sb = 31 - (int)blockIdx.y;  // LPT: big superblocks dispatch first
  const int lane = threadIdx.x & 63;
  const int q31 = lane & 31, hi = lane >> 5;
  const int qA = sb * 64 + q31;        // MFMA block A row
  const int qBr = sb * 64 + 32 + q31;  // MFMA block B row
  const u16* Qh = Qb + (size_t)bh * 2048 * 64;
  const u16* Kh = Kb + (size_t)bh * 2048 * 64;
  const u16* Vh = VTb + (size_t)bh * 64 * 2048;
  const int b = bh >> 4, h = bh & 15;

  bf16x8 qfA[4], qfB[4];
#pragma unroll
  for (int d = 0; d < 4; ++d) {
    qfA[d] = *(const bf16x8*)(&Qh[(size_t)qA * 64 + d * 16 + hi * 8]);
    qfB[d] = *(const bf16x8*)(&Qh[(size_t)qBr * 64 + d * 16 + hi * 8]);
  }

  f32x16 oA0 = (f32x16)0.0f, oA1 = (f32x16)0.0f;
  f32x16 oB0 = (f32x16)0.0f, oB1 = (f32x16)0.0f;
  float mA = -1e30f, sA = 0.0f, mB = -1e30f, sB = 0.0f;

  const int nt = 2 * sb + 2;
  // preload tile 0's K
  bf16x8 kf[4];
#pragma unroll
  for (int d = 0; d < 4; ++d)
    kf[d] = *(const bf16x8*)(&Kh[(size_t)q31 * 64 + d * 16 + hi * 8]);

  for (int tt = 0; tt < nt; ++tt) {
    const int j0 = tt * 32;
    const bool aAct = tt < nt - 1;  // A's rows end at tile nt-2

    // ---- prefetch next tile's K (clamped re-read on last); V for current ----
    const int jn = (tt + 1 < nt) ? j0 + 32 : j0;
    bf16x8 kn[4];
#pragma unroll
    for (int d = 0; d < 4; ++d)
      kn[d] = *(const bf16x8*)(&Kh[(size_t)(jn + q31) * 64 + d * 16 + hi * 8]);
    const bf16x8 vf0 = *(const bf16x8*)(&Vh[(size_t)q31 * 2048 + j0 + hi * 8]);
    const bf16x8 vf1 = *(const bf16x8*)(&Vh[(size_t)q31 * 2048 + j0 + 16 + hi * 8]);
    const bf16x8 vf2 = *(const bf16x8*)(&Vh[(size_t)(32 + q31) * 2048 + j0 + hi * 8]);
    const bf16x8 vf3 = *(const bf16x8*)(&Vh[(size_t)(32 + q31) * 2048 + j0 + 16 + hi * 8]);

    f32x16 stB = (f32x16)0.0f;
    __builtin_amdgcn_s_setprio(1);
#pragma unroll
    for (int d = 0; d < 4; ++d) stB = MFMA32(kf[d], qfB[d], stB);
    f32x16 stA = (f32x16)0.0f;
    if (aAct) {
#pragma unroll
      for (int d = 0; d < 4; ++d) stA = MFMA32(kf[d], qfA[d], stA);
    }
    __builtin_amdgcn_s_setprio(0);

    if (tt == nt - 2) {
#pragma unroll
      for (int r = 0; r < 16; ++r) {
        const int kcol = (r & 3) + 8 * (r >> 2) + 4 * hi;
        if (kcol > q31) stA[r] = -1e30f;
      }
    }
    if (tt == nt - 1) {
#pragma unroll
      for (int r = 0; r < 16; ++r) {
        const int kcol = (r & 3) + 8 * (r >> 2) + 4 * hi;
        if (kcol > q31) stB[r] = -1e30f;
      }
    }

    union { u32 w4[4]; bf16x8 f; } paA0, paA1, paB0, paB1;
    if (aAct) {
      float mx = fmaxf(
          fmaxf(fmaxf(fmaxf(stA[0], stA[1]), fmaxf(stA[2], stA[3])),
                fmaxf(fmaxf(stA[4], stA[5]), fmaxf(stA[6], stA[7]))),
          fmaxf(fmaxf(fmaxf(stA[8], stA[9]), fmaxf(stA[10], stA[11])),
                fmaxf(fmaxf(stA[12], stA[13]), fmaxf(stA[14], stA[15]))));
      if (__any(mx - mA > 8.0f)) {
        mx = fmaxf(mx, __shfl_xor(mx, 32));
        const float mn = fmaxf(mA, mx);
        const float scf = exp2a(mA - mn);
        mA = mn; sA *= scf; oA0 *= scf; oA1 *= scf;
      }
      float p[16];
#pragma unroll
      for (int r = 0; r < 16; ++r) p[r] = exp2a(stA[r] - mA);
      sA += (((p[0] + p[1]) + (p[2] + p[3])) + ((p[4] + p[5]) + (p[6] + p[7]))) +
            (((p[8] + p[9]) + (p[10] + p[11])) + ((p[12] + p[13]) + (p[14] + p[15])));
      u32 D0 = cvtpk(p[0], p[1]),   D1 = cvtpk(p[2], p[3]);
      u32 D2 = cvtpk(p[4], p[5]),   D3 = cvtpk(p[6], p[7]);
      u32 D4 = cvtpk(p[8], p[9]),   D5 = cvtpk(p[10], p[11]);
      u32 D6 = cvtpk(p[12], p[13]), D7 = cvtpk(p[14], p[15]);
      u32x2 s02 = __builtin_amdgcn_permlane32_swap(D0, D2, false, false);
      u32x2 s13 = __builtin_amdgcn_permlane32_swap(D1, D3, false, false);
      u32x2 s46 = __builtin_amdgcn_permlane32_swap(D4, D6, false, false);
      u32x2 s57 = __builtin_amdgcn_permlane32_swap(D5, D7, false, false);
      paA0.w4[0] = s02.x; paA0.w4[1] = s13.x; paA0.w4[2] = s02.y; paA0.w4[3] = s13.y;
      paA1.w4[0] = s46.x; paA1.w4[1] = s57.x; paA1.w4[2] = s46.y; paA1.w4[3] = s57.y;
    }

    {
      float mx = fmaxf(
          fmaxf(fmaxf(fmaxf(stB[0], stB[1]), fmaxf(stB[2], stB[3])),
                fmaxf(fmaxf(stB[4], stB[5]), fmaxf(stB[6], stB[7]))),
          fmaxf(fmaxf(fmaxf(stB[8], stB[9]), fmaxf(stB[10], stB[11])),
                fmaxf(fmaxf(stB[12], stB[13]), fmaxf(stB[14], stB[15]))));
      if (__any(mx - mB > 8.0f)) {
        mx = fmaxf(mx, __shfl_xor(mx, 32));
        const float mn = fmaxf(mB, mx);
        const float scf = exp2a(mB - mn);
        mB = mn; sB *= scf; oB0 *= scf; oB1 *= scf;
      }
      float p[16];
#pragma unroll
      for (int r = 0; r < 16; ++r) p[r] = exp2a(stB[r] - mB);
      sB += (((p[0] + p[1]) + (p[2] + p[3])) + ((p[4] + p[5]) + (p[6] + p[7]))) +
            (((p[8] + p[9]) + (p[10] + p[11])) + ((p[12] + p[13]) + (p[14] + p[15])));
      u32 D0 = cvtpk(p[0], p[1]),   D1 = cvtpk(p[2], p[3]);
      u32 D2 = cvtpk(p[4], p[5]),   D3 = cvtpk(p[6], p[7]);
      u32 D4 = cvtpk(p[8], p[9]),   D5 = cvtpk(p[10], p[11]);
      u32 D6 = cvtpk(p[12], p[13]), D7 = cvtpk(p[14], p[15]);
      u32x2 s02 = __builtin_amdgcn_permlane32_swap(D0, D2, false, false);
      u32x2 s13 = __builtin_amdgcn_permlane32_swap(D1, D3, false, false);
      u32x2 s46 = __builtin_amdgcn_permlane32_swap(D4, D6, false, false);
      u32x2 s57 = __builtin_amdgcn_permlane32_swap(D5, D7, false, false);
      paB0.w4[0] = s02.x; paB0.w4[1] = s13.x; paB0.w4[2] = s02.y; paB0.w4[3] = s13.y;
      paB1.w4[0] = s46.x; paB1.w4[1] = s57.x; paB1.w4[2] = s46.y; paB1.w4[3] = s57.y;
    }

    __builtin_amdgcn_s_setprio(1);
    oB0 = MFMA32(vf0, paB0.f, oB0);
    oB0 = MFMA32(vf1, paB1.f, oB0);
    oB1 = MFMA32(vf2, paB0.f, oB1);
    oB1 = MFMA32(vf3, paB1.f, oB1);
    if (aAct) {
      oA0 = MFMA32(vf0, paA0.f, oA0);
      oA0 = MFMA32(vf1, paA1.f, oA0);
      oA1 = MFMA32(vf2, paA0.f, oA1);
      oA1 = MFMA32(vf3, paA1.f, oA1);
    }
    __builtin_amdgcn_s_setprio(0);

    // rotate prefetched K
#pragma unroll
    for (int d = 0; d < 4; ++d) kf[d] = kn[d];
  }

  sA += __shfl_xor(sA, 32);
  sB += __shfl_xor(sB, 32);
  const float invA = 1.0f / sA, invB = 1.0f / sB;
  u16* yrowA = Y + ((size_t)b * 2048 + qA) * 1024 + h * 64;
  u16* yrowB = Y + ((size_t)b * 2048 + qBr) * 1024 + h * 64;
#pragma unroll
  for (int a = 0; a < 4; ++a) {
    u16x4 pk;
#pragma unroll
    for (int i = 0; i < 4; ++i) pk[i] = f2bf(oA0[a * 4 + i] * invA);
    *(u16x4*)(yrowA + a * 8 + 4 * hi) = pk;
#pragma unroll
    for (int i = 0; i < 4; ++i) pk[i] = f2bf(oA1[a * 4 + i] * invA);
    *(u16x4*)(yrowA + 32 + a * 8 + 4 * hi) = pk;
#pragma unroll
    for (int i = 0; i < 4; ++i) pk[i] = f2bf(oB0[a * 4 + i] * invB);
    *(u16x4*)(yrowB + a * 8 + 4 * hi) = pk;
#pragma unroll
    for (int i = 0; i < 4; ++i) pk[i] = f2bf(oB1[a * 4 + i] * invB);
    *(u16x4*)(yrowB + 32 + a * 8 + 4 * hi) = pk;
  }
}

extern "C" void kernel_launch(void* const* d_in, const int* in_sizes, int n_in,
                              void* d_out, int out_size, void* d_ws, size_t ws_size,
                              hipStream_t stream) {
  const float* x      = (const float*)d_in[0];  // [4,2048,1024] fp32
  const float* w_qkv  = (const float*)d_in[1];  // [1024,3072]   fp32
  const float* w_proj = (const float*)d_in[2];  // [1024,1024]   fp32
  const float* b_proj = (const float*)d_in[3];  // [1024]        fp32
  float* out = (float*)d_out;                   // [4,2048,1024] fp32

  char* ws = (char*)d_ws;
  u16* wqkvT  = (u16*)(ws);             // [3072][1024] bf16  6.29 MB
  u16* wprojT = (u16*)(ws + 6291456);   // [1024][1024] bf16  2.10 MB
  u16* Qb     = (u16*)(ws + 8388608);   // [64][2048][64]    16.78 MB
  u16* Kb     = (u16*)(ws + 25165824);  // [64][2048][64]    16.78 MB
  u16* VTb    = (u16*)(ws + 41943040);  // [64][64][2048]    16.78 MB
  u16* xb     = (u16*)(ws + 58720256);  // [8192][1024] bf16 16.78 MB (aliased: xb then Yb)
  u16* Yb     = xb;                     // xb dead after GEMM1; attn writes Yb

  k_prep<<<5120, 256, 0, stream>>>(x, xb, w_qkv, wqkvT, w_proj, wprojT);
  k_gemm<1><<<1536, 256, 0, stream>>>(xb, wqkvT, nullptr, nullptr,
                                      Qb, Kb, VTb, 8192, 3072, 1024, 24);
  k_attn<<<dim3(64, 32), 64, 0, stream>>>(Qb, Kb, VTb, Yb);
  k_gemm<0><<<512, 256, 0, stream>>>(Yb, wprojT, b_proj, out,
                                     nullptr, nullptr, nullptr, 8192, 1024, 1024, 8);
}